// Round 6
// baseline (655.466 us; speedup 1.0000x reference)
//
#include <hip/hip_runtime.h>
#include <hip/hip_bf16.h>

// Problem constants (B=2, T=2048, C=2048, NH=16, L=128)
#define B_   2
#define T_   2048
#define C_   2048
#define NH_  16
#define L_   128
#define NKQ  2176   // L_ + NH_*L_
#define MTOK 4096   // B_*T_
#define SCALE_ 0.08838834764831845f           // 1/sqrt(128)
#define SCALE2_ 0.12753785792696073f          // SCALE_ * log2(e)

typedef short short8 __attribute__((ext_vector_type(8)));
typedef float f32x4  __attribute__((ext_vector_type(4)));

// async global->LDS, 16B per lane; LDS base must be wave-uniform.
#define GLD16(gp, lp) __builtin_amdgcn_global_load_lds(                      \
    (const __attribute__((address_space(1))) void*)(gp),                     \
    (__attribute__((address_space(3))) void*)(lp), 16, 0, 0)

__device__ __forceinline__ unsigned short f2bf(float f) {
  union { float f; unsigned u; } x; x.f = f;
  unsigned r = x.u + 0x7fffu + ((x.u >> 16) & 1u);   // RNE
  return (unsigned short)(r >> 16);
}

// ---------------- fp32 -> bf16 convert (n % 4 == 0) ----------------
__global__ void cvt_f32_bf16(const float* __restrict__ in,
                             unsigned short* __restrict__ out, int n) {
  int i = (blockIdx.x * blockDim.x + threadIdx.x) * 4;
  if (i >= n) return;
  float4 v = *(const float4*)(in + i);
  ushort4 o;
  o.x = f2bf(v.x); o.y = f2bf(v.y); o.z = f2bf(v.z); o.w = f2bf(v.w);
  *(ushort4*)(out + i) = o;
}

// ------------- transpose W[K][N] fp32 -> Wt[N][K] bf16 (x mul) -------------
__global__ void transpose_to_bf16(const float* __restrict__ W,
                                  unsigned short* __restrict__ Wt,
                                  int K, int N, float mul) {
  __shared__ float tile[32][33];
  int bx = blockIdx.x * 32;  // along N
  int by = blockIdx.y * 32;  // along K
  int tx = threadIdx.x, ty = threadIdx.y;
  #pragma unroll
  for (int i = 0; i < 4; i++)
    tile[ty + i * 8][tx] = W[(size_t)(by + ty + i * 8) * N + bx + tx];
  __syncthreads();
  #pragma unroll
  for (int i = 0; i < 4; i++)
    Wt[(size_t)(bx + ty + i * 8) * K + by + tx] = f2bf(tile[tx][ty + i * 8] * mul);
}

// ---- transpose latent cols of kq -> KlT[b][l][t] (bf16) ----
__global__ void transpose_lat(const unsigned short* __restrict__ kq,
                              unsigned short* __restrict__ KlT) {
  __shared__ unsigned short tile[32][33];
  int t0 = blockIdx.x * 32, l0 = blockIdx.y * 32, b = blockIdx.z;
  int tx = threadIdx.x, ty = threadIdx.y;
  #pragma unroll
  for (int i = 0; i < 4; i++)
    tile[ty + i * 8][tx] = kq[((size_t)b * T_ + t0 + ty + i * 8) * NKQ + l0 + tx];
  __syncthreads();
  #pragma unroll
  for (int i = 0; i < 4; i++)
    KlT[((size_t)b * L_ + l0 + ty + i * 8) * T_ + t0 + tx] = tile[tx][ty + i * 8];
}

// ---------------- concat bias [b_lat | scale*log2e*b_d] ----------------
__global__ void make_bias_cat(const float* __restrict__ b_lat,
                              const float* __restrict__ b_d,
                              float* __restrict__ out) {
  int i = blockIdx.x * blockDim.x + threadIdx.x;
  if (i < L_) out[i] = b_lat[i];
  else if (i < NKQ) out[i] = b_d[i - L_] * SCALE2_;
}

// ---------------- bf16 MFMA GEMM (m97 structure):  C = A @ Bt^T + bias ----------------
__global__ __launch_bounds__(256) void gemm_bt_bias(
    const unsigned short* __restrict__ A,   // [M][K] bf16
    const unsigned short* __restrict__ Bt,  // [N][K] bf16
    const float* __restrict__ bias,         // [N]
    unsigned short* __restrict__ Cb,        // bf16 out (or null)
    float* __restrict__ Cf,                 // fp32 out (or null)
    int M, int N, int K) {
  __shared__ __align__(16) unsigned short As[128 * 32];  // unpadded, BK=32
  __shared__ __align__(16) unsigned short Bs[128 * 32];
  const int tid  = threadIdx.x;
  const int wave = tid >> 6, lane = tid & 63;
  const int lcol = lane & 15, quad = lane >> 4;
  const int m0 = blockIdx.x * 128, n0 = blockIdx.y * 128;
  const int wm = (wave >> 1) * 64, wn = (wave & 1) * 64;
  const int lrow = lane >> 2, lchunk = (lane & 3) * 8;

  f32x4 acc[4][4];
  #pragma unroll
  for (int i = 0; i < 4; i++)
    #pragma unroll
    for (int j = 0; j < 4; j++) acc[i][j] = (f32x4){0.f, 0.f, 0.f, 0.f};

  for (int kc = 0; kc < K; kc += 32) {
    __syncthreads();
    {
      int rb = wave * 32;
      GLD16(&A [(size_t)(m0 + rb      + lrow) * K + kc + lchunk], &As[ rb       * 32]);
      GLD16(&A [(size_t)(m0 + rb + 16 + lrow) * K + kc + lchunk], &As[(rb + 16) * 32]);
      GLD16(&Bt[(size_t)(n0 + rb      + lrow) * K + kc + lchunk], &Bs[ rb       * 32]);
      GLD16(&Bt[(size_t)(n0 + rb + 16 + lrow) * K + kc + lchunk], &Bs[(rb + 16) * 32]);
    }
    __syncthreads();
    short8 af[4], bfr[4];
    #pragma unroll
    for (int i = 0; i < 4; i++)
      af[i] = *(const short8*)&As[(wm + i * 16 + lcol) * 32 + quad * 8];
    #pragma unroll
    for (int j = 0; j < 4; j++)
      bfr[j] = *(const short8*)&Bs[(wn + j * 16 + lcol) * 32 + quad * 8];
    #pragma unroll
    for (int i = 0; i < 4; i++)
      #pragma unroll
      for (int j = 0; j < 4; j++)
        acc[i][j] = __builtin_amdgcn_mfma_f32_16x16x32_bf16(af[i], bfr[j], acc[i][j], 0, 0, 0);
  }

  #pragma unroll
  for (int i = 0; i < 4; i++) {
    #pragma unroll
    for (int j = 0; j < 4; j++) {
      int col = n0 + wn + j * 16 + lcol;
      float bv = bias[col];
      #pragma unroll
      for (int r = 0; r < 4; r++) {
        int row = m0 + wm + i * 16 + quad * 4 + r;
        float v = acc[i][j][r] + bv;
        if (Cf) Cf[(size_t)row * N + col] = v;
        else    Cb[(size_t)row * N + col] = f2bf(v);
      }
    }
  }
}

// ---------------- fused causal MLA attention (M=64/wave, 2-way s-split) ----------------
// Block = 4 waves = 2 heads x 2 s-partitions; 64 q-rows per job.
// Per step two s-tiles staged (even->buf0, odd->buf1); partition p computes
// tile 2j+p from buf p. No-max softmax => partitions merge by pure addition
// of O and lsum in an LDS epilogue (no rescaling).
// Grid 512: n<256 heavy (qt=31-qi), n>=256 light (qt=qi); 80KB LDS = 2 blk/CU.
__global__ __launch_bounds__(256, 2) void attn_mla(
    const unsigned short* __restrict__ kq,   // [B*T][NKQ]
    const unsigned short* __restrict__ KlT,  // [B][L][T]
    unsigned short* __restrict__ y) {        // [B*T][NH*L]
  __shared__ __align__(16) unsigned char smem[81920];
  unsigned short* KrS  = (unsigned short*)smem;            // [2][64*128]  32KB
  unsigned short* KtS  = (unsigned short*)(smem + 32768);  // [2][128*64]  32KB
  unsigned short* Pall = (unsigned short*)(smem + 65536);  // [4][64*32]   16KB
  // epilogue aliases (used only after a full barrier once compute is done):
  float* Oex = (float*)smem;                               // [2][64*64] fp32 32KB
  float* lsx = (float*)(smem + 65536);                     // [2][2][64]  1KB

  const int tid  = threadIdx.x;
  const int wave = tid >> 6, lane = tid & 63;
  const int lcol = lane & 15, quad = lane >> 4;
  const int gid  = blockIdx.x;
  const int slot = gid >> 8, c = gid & 255;
  const int b    = c >> 7;
  const int hp   = (c >> 4) & 7;
  const int qi   = c & 15;
  const int qt   = slot ? qi : (31 - qi);   // 64-row q-tile index, 0..31
  const int head_sub = wave >> 1;           // 0..1
  const int part     = wave & 1;            // s-partition
  const int h    = hp * 2 + head_sub;
  const size_t rowbase = (size_t)b * T_;
  const int q0 = qt * 64;
  unsigned short* Pw = Pall + wave * 64 * 32;

  // Q fragments (A-layout m=lane&15, k=quad*8+j); scale*log2e pre-folded
  short8 qf[4][4];
  #pragma unroll
  for (int i = 0; i < 4; i++) {
    const unsigned short* qp = kq + (rowbase + q0 + i * 16 + lcol) * NKQ + L_ + h * L_;
    #pragma unroll
    for (int kc = 0; kc < 4; kc++)
      qf[i][kc] = *(const short8*)(qp + kc * 32 + quad * 8);
  }

  f32x4 acco[4][8];
  #pragma unroll
  for (int i = 0; i < 4; i++)
    #pragma unroll
    for (int ns = 0; ns < 8; ns++) acco[i][ns] = (f32x4){0.f, 0.f, 0.f, 0.f};
  float lsum[4][4];
  #pragma unroll
  for (int i = 0; i < 4; i++)
    #pragma unroll
    for (int r = 0; r < 4; r++) lsum[i][r] = 0.f;

  const int nt = qt + 1;                 // s-tiles of 64
  const int steps = (nt + 1) >> 1;

  for (int j = 0; j < steps; j++) {
    __syncthreads();  // previous step's compute done -> buffers reusable
    // stage: wave0 Kr(even), wave1 Kt(even), wave2 Kr(odd), wave3 Kt(odd)
    {
      int t = 2 * j + (wave >> 1);       // wave0,1 -> even; wave2,3 -> odd
      if (t < nt) {
        int s0t = t * 64;
        if ((wave & 1) == 0) {           // Kr: [s 64][l 128], swizzled per row
          unsigned short* dst = KrS + (wave >> 1) * (64 * 128);
          #pragma unroll
          for (int kk = 0; kk < 16; kk++) {
            int rg = kk * 4 + (lane >> 4);
            int cl = ((lane & 15) ^ (rg & 7)) * 8;
            GLD16(kq + (rowbase + s0t + rg) * NKQ + cl, dst + kk * 4 * 128);
          }
        } else {                         // Kt: [l 128][s 64], swizzled per row
          unsigned short* dst = KtS + (wave >> 1) * (128 * 64);
          #pragma unroll
          for (int kk = 0; kk < 16; kk++) {
            int rg = kk * 8 + (lane >> 3);
            int cl = ((lane & 7) ^ (rg & 7)) * 8;
            GLD16(KlT + ((size_t)b * L_ + rg) * T_ + s0t + cl, dst + kk * 8 * 64);
          }
        }
      }
    }
    __syncthreads();  // staging complete

    const int tw = 2 * j + part;
    if (tw < nt) {
      const unsigned short* Krc = KrS + part * (64 * 128);
      const unsigned short* Ktc = KtS + part * (128 * 64);
      const bool diag = (tw == qt);

      #pragma unroll
      for (int h2 = 0; h2 < 2; h2++) {   // s-halves of 32 within the tile
        // S(64x32) = Q @ K^T for this half
        f32x4 accs[4][2];
        #pragma unroll
        for (int i = 0; i < 4; i++)
          #pragma unroll
          for (int n2 = 0; n2 < 2; n2++) accs[i][n2] = (f32x4){0.f, 0.f, 0.f, 0.f};
        #pragma unroll
        for (int kc = 0; kc < 4; kc++)
          #pragma unroll
          for (int n2 = 0; n2 < 2; n2++) {
            int ns = h2 * 2 + n2;
            short8 bfrag = *(const short8*)&Krc[(ns * 16 + lcol) * 128 +
                                                (((kc * 4 + quad) ^ (lcol & 7)) * 8)];
            #pragma unroll
            for (int i = 0; i < 4; i++)
              accs[i][n2] = __builtin_amdgcn_mfma_f32_16x16x32_bf16(qf[i][kc], bfrag, accs[i][n2], 0, 0, 0);
          }

        // p = 2^s, mask on diag; write P half [64 rows][32 cols]
        #pragma unroll
        for (int i = 0; i < 4; i++)
          #pragma unroll
          for (int n2 = 0; n2 < 2; n2++)
            #pragma unroll
            for (int r = 0; r < 4; r++) {
              float v = accs[i][n2][r];
              int sg = h2 * 32 + n2 * 16 + lcol;      // s rel (s0==q0 on diag)
              int qg = i * 16 + quad * 4 + r;         // q rel
              if (diag && sg > qg) v = -1e30f;
              float e = __builtin_amdgcn_exp2f(v);
              unsigned eu = __float_as_uint(e) & 0xffff0000u;
              lsum[i][r] += __uint_as_float(eu);
              int row = i * 16 + quad * 4 + r;
              int col = n2 * 16 + lcol;
              int phys = (col >> 3) ^ ((row >> 1) & 3);
              Pw[row * 32 + phys * 8 + (col & 7)] = (unsigned short)(eu >> 16);
            }

        // O(64x128) += P(64x32) @ K(32x128) for this half
        short8 pa[4];
        #pragma unroll
        for (int i = 0; i < 4; i++)
          pa[i] = *(const short8*)&Pw[(i * 16 + lcol) * 32 +
                                      ((quad ^ ((lcol >> 1) & 3)) * 8)];
        #pragma unroll
        for (int ns = 0; ns < 8; ns++) {
          short8 bfrag = *(const short8*)&Ktc[(ns * 16 + lcol) * 64 +
                                              (((h2 * 4 + quad) ^ (lcol & 7)) * 8)];
          #pragma unroll
          for (int i = 0; i < 4; i++)
            acco[i][ns] = __builtin_amdgcn_mfma_f32_16x16x32_bf16(pa[i], bfrag, acco[i][ns], 0, 0, 0);
        }
      }
    }
  }

  // ---- epilogue: merge the two s-partitions (pure adds), normalize, write ----
  // reduce lsum over the 16 lcol lanes
  #pragma unroll
  for (int i = 0; i < 4; i++)
    #pragma unroll
    for (int r = 0; r < 4; r++) {
      float s = lsum[i][r];
      #pragma unroll
      for (int off = 1; off < 16; off <<= 1) s += __shfl_xor(s, off, 64);
      lsum[i][r] = s;
    }

  __syncthreads();  // all compute done -> safe to alias Kr/P regions
  if (lcol == 0) {
    #pragma unroll
    for (int i = 0; i < 4; i++)
      #pragma unroll
      for (int r = 0; r < 4; r++)
        lsx[(head_sub * 2 + part) * 64 + i * 16 + quad * 4 + r] = lsum[i][r];
  }
  float* Oh = Oex + head_sub * (64 * 64);
  if (part == 1) {  // phase 1: partition B ships O cols [0,64)
    #pragma unroll
    for (int i = 0; i < 4; i++)
      #pragma unroll
      for (int ns = 0; ns < 4; ns++)
        #pragma unroll
        for (int r = 0; r < 4; r++)
          Oh[(i * 16 + quad * 4 + r) * 64 + ns * 16 + lcol] = acco[i][ns][r];
  }
  __syncthreads();
  float inv[4][4];
  #pragma unroll
  for (int i = 0; i < 4; i++)
    #pragma unroll
    for (int r = 0; r < 4; r++) {
      int row = i * 16 + quad * 4 + r;
      inv[i][r] = 1.f / (lsx[(head_sub * 2) * 64 + row] + lsx[(head_sub * 2 + 1) * 64 + row]);
    }
  if (part == 0) {  // A absorbs B's cols [0,64)
    #pragma unroll
    for (int i = 0; i < 4; i++)
      #pragma unroll
      for (int ns = 0; ns < 4; ns++)
        #pragma unroll
        for (int r = 0; r < 4; r++)
          acco[i][ns][r] += Oh[(i * 16 + quad * 4 + r) * 64 + ns * 16 + lcol];
  }
  __syncthreads();
  if (part == 0) {  // phase 2: A ships O cols [64,128)
    #pragma unroll
    for (int i = 0; i < 4; i++)
      #pragma unroll
      for (int ns = 4; ns < 8; ns++)
        #pragma unroll
        for (int r = 0; r < 4; r++)
          Oh[(i * 16 + quad * 4 + r) * 64 + (ns - 4) * 16 + lcol] = acco[i][ns][r];
  }
  __syncthreads();
  if (part == 1) {
    #pragma unroll
    for (int i = 0; i < 4; i++)
      #pragma unroll
      for (int ns = 4; ns < 8; ns++)
        #pragma unroll
        for (int r = 0; r < 4; r++)
          acco[i][ns][r] += Oh[(i * 16 + quad * 4 + r) * 64 + (ns - 4) * 16 + lcol];
  }
  // write y: part 0 -> cols [0,64), part 1 -> cols [64,128)
  const int nsb = part * 4;
  #pragma unroll
  for (int i = 0; i < 4; i++)
    #pragma unroll
    for (int ns = 0; ns < 4; ns++)
      #pragma unroll
      for (int r = 0; r < 4; r++) {
        int qg = q0 + i * 16 + quad * 4 + r;
        y[(rowbase + qg) * (NH_ * L_) + h * L_ + (nsb + ns) * 16 + lcol] =
            f2bf(acco[i][nsb + ns][r] * inv[i][r]);
      }
}

extern "C" void kernel_launch(void* const* d_in, const int* in_sizes, int n_in,
                              void* d_out, int out_size, void* d_ws, size_t ws_size,
                              hipStream_t stream) {
  const float* x      = (const float*)d_in[0];
  const float* W_lat  = (const float*)d_in[1];
  const float* b_lat  = (const float*)d_in[2];
  const float* W_d    = (const float*)d_in[3];
  const float* b_d    = (const float*)d_in[4];
  const float* W_proj = (const float*)d_in[5];
  const float* b_proj = (const float*)d_in[6];
  float* out = (float*)d_out;

  // workspace layout (bf16 buffers, 16B aligned)
  unsigned short* x_bf   = (unsigned short*)d_ws;                  // [4096][2048]
  unsigned short* BtCat  = x_bf   + (size_t)MTOK * C_;             // [2176][2048]
  unsigned short* WprojT = BtCat  + (size_t)NKQ * C_;              // [2048][2048]
  unsigned short* kqbuf  = WprojT + (size_t)C_ * (NH_ * L_);       // [4096][2176]
  unsigned short* ybuf   = kqbuf  + (size_t)MTOK * NKQ;            // [4096][2048]
  unsigned short* KlT    = ybuf   + (size_t)MTOK * (NH_ * L_);     // [2][128][2048]
  float*          biascat = (float*)(KlT + (size_t)B_ * L_ * T_);  // [2176]

  // 1. x -> bf16
  cvt_f32_bf16<<<(MTOK * C_) / 1024, 256, 0, stream>>>(x, x_bf, MTOK * C_);
  // 2. weights -> transposed bf16 (Bt layout); fold scale*log2e into W_d
  transpose_to_bf16<<<dim3(L_ / 32, C_ / 32), dim3(32, 8), 0, stream>>>(W_lat, BtCat, C_, L_, 1.f);
  transpose_to_bf16<<<dim3((NH_ * L_) / 32, C_ / 32), dim3(32, 8), 0, stream>>>(
      W_d, BtCat + (size_t)L_ * C_, C_, NH_ * L_, SCALE2_);
  transpose_to_bf16<<<dim3(C_ / 32, (NH_ * L_) / 32), dim3(32, 8), 0, stream>>>(
      W_proj, WprojT, NH_ * L_, C_, 1.f);
  make_bias_cat<<<(NKQ + 255) / 256, 256, 0, stream>>>(b_lat, b_d, biascat);
  // 3. kq = x @ [W_lat | scale*log2e*W_d] + bias (bf16 out)
  gemm_bt_bias<<<dim3(MTOK / 128, NKQ / 128), 256, 0, stream>>>(
      x_bf, BtCat, biascat, kqbuf, nullptr, MTOK, NKQ, C_);
  // 4. latent transpose for PV staging
  transpose_lat<<<dim3(T_ / 32, L_ / 32, B_), dim3(32, 8), 0, stream>>>(kqbuf, KlT);
  // 5. causal MLA attention (512 balanced blocks, M=64/wave, s-split)
  attn_mla<<<512, 256, 0, stream>>>(kqbuf, KlT, ybuf);
  // 6. out = y @ W_proj + b_proj (fp32 out)
  gemm_bt_bias<<<dim3(MTOK / 128, C_ / 128), 256, 0, stream>>>(
      ybuf, WprojT, b_proj, nullptr, out, MTOK, C_, C_);
}

// Round 7
// 314.988 us; speedup vs baseline: 2.0809x; 2.0809x over previous
//
#include <hip/hip_runtime.h>
#include <hip/hip_bf16.h>

// Problem constants (B=2, T=2048, C=2048, NH=16, L=128)
#define B_   2
#define T_   2048
#define C_   2048
#define NH_  16
#define L_   128
#define NKQ  2176   // L_ + NH_*L_
#define MTOK 4096   // B_*T_
#define SCALE_ 0.08838834764831845f           // 1/sqrt(128)
#define SCALE2_ 0.12753785792696073f          // SCALE_ * log2(e)

typedef short short8 __attribute__((ext_vector_type(8)));
typedef float f32x4  __attribute__((ext_vector_type(4)));

// async global->LDS, 16B per lane; LDS base must be wave-uniform.
#define GLD16(gp, lp) __builtin_amdgcn_global_load_lds(                      \
    (const __attribute__((address_space(1))) void*)(gp),                     \
    (__attribute__((address_space(3))) void*)(lp), 16, 0, 0)

__device__ __forceinline__ unsigned short f2bf(float f) {
  union { float f; unsigned u; } x; x.f = f;
  unsigned r = x.u + 0x7fffu + ((x.u >> 16) & 1u);   // RNE
  return (unsigned short)(r >> 16);
}

// ---------------- fp32 -> bf16 convert (n % 4 == 0) ----------------
__global__ void cvt_f32_bf16(const float* __restrict__ in,
                             unsigned short* __restrict__ out, int n) {
  int i = (blockIdx.x * blockDim.x + threadIdx.x) * 4;
  if (i >= n) return;
  float4 v = *(const float4*)(in + i);
  ushort4 o;
  o.x = f2bf(v.x); o.y = f2bf(v.y); o.z = f2bf(v.z); o.w = f2bf(v.w);
  *(ushort4*)(out + i) = o;
}

// ------------- transpose W[K][N] fp32 -> Wt[N][K] bf16 (x mul) -------------
__global__ void transpose_to_bf16(const float* __restrict__ W,
                                  unsigned short* __restrict__ Wt,
                                  int K, int N, float mul) {
  __shared__ float tile[32][33];
  int bx = blockIdx.x * 32;  // along N
  int by = blockIdx.y * 32;  // along K
  int tx = threadIdx.x, ty = threadIdx.y;
  #pragma unroll
  for (int i = 0; i < 4; i++)
    tile[ty + i * 8][tx] = W[(size_t)(by + ty + i * 8) * N + bx + tx];
  __syncthreads();
  #pragma unroll
  for (int i = 0; i < 4; i++)
    Wt[(size_t)(bx + ty + i * 8) * K + by + tx] = f2bf(tile[tx][ty + i * 8] * mul);
}

// ---- transpose latent cols of kq -> KlT[b][l][t] (bf16) ----
__global__ void transpose_lat(const unsigned short* __restrict__ kq,
                              unsigned short* __restrict__ KlT) {
  __shared__ unsigned short tile[32][33];
  int t0 = blockIdx.x * 32, l0 = blockIdx.y * 32, b = blockIdx.z;
  int tx = threadIdx.x, ty = threadIdx.y;
  #pragma unroll
  for (int i = 0; i < 4; i++)
    tile[ty + i * 8][tx] = kq[((size_t)b * T_ + t0 + ty + i * 8) * NKQ + l0 + tx];
  __syncthreads();
  #pragma unroll
  for (int i = 0; i < 4; i++)
    KlT[((size_t)b * L_ + l0 + ty + i * 8) * T_ + t0 + tx] = tile[tx][ty + i * 8];
}

// ---------------- concat bias [b_lat | scale*log2e*b_d] ----------------
__global__ void make_bias_cat(const float* __restrict__ b_lat,
                              const float* __restrict__ b_d,
                              float* __restrict__ out) {
  int i = blockIdx.x * blockDim.x + threadIdx.x;
  if (i < L_) out[i] = b_lat[i];
  else if (i < NKQ) out[i] = b_d[i - L_] * SCALE2_;
}

// ---------------- bf16 MFMA GEMM, 128x64 tile:  C = A @ Bt^T + bias ----------------
// 4 waves, each 64x32 (4x2 of 16x16x32). More blocks than 128x128 -> better
// occupancy (grid was the binding constraint at 544 blocks).
__global__ __launch_bounds__(256) void gemm_bt_bias64(
    const unsigned short* __restrict__ A,   // [M][K] bf16
    const unsigned short* __restrict__ Bt,  // [N][K] bf16
    const float* __restrict__ bias,         // [N]
    unsigned short* __restrict__ Cb,        // bf16 out (or null)
    float* __restrict__ Cf,                 // fp32 out (or null)
    int M, int N, int K) {
  __shared__ __align__(16) unsigned short As[128 * 32];  // 8 KB
  __shared__ __align__(16) unsigned short Bs[64 * 32];   // 4 KB
  const int tid  = threadIdx.x;
  const int wave = tid >> 6, lane = tid & 63;
  const int lcol = lane & 15, quad = lane >> 4;
  const int m0 = blockIdx.x * 128, n0 = blockIdx.y * 64;
  const int wm = (wave >> 1) * 64, wn = (wave & 1) * 32;
  const int lrow = lane >> 2, lchunk = (lane & 3) * 8;

  f32x4 acc[4][2];
  #pragma unroll
  for (int i = 0; i < 4; i++)
    #pragma unroll
    for (int j = 0; j < 2; j++) acc[i][j] = (f32x4){0.f, 0.f, 0.f, 0.f};

  for (int kc = 0; kc < K; kc += 32) {
    __syncthreads();
    {
      int rb = wave * 32;
      GLD16(&A [(size_t)(m0 + rb      + lrow) * K + kc + lchunk], &As[ rb       * 32]);
      GLD16(&A [(size_t)(m0 + rb + 16 + lrow) * K + kc + lchunk], &As[(rb + 16) * 32]);
      GLD16(&Bt[(size_t)(n0 + wave * 16 + lrow) * K + kc + lchunk], &Bs[(wave * 16) * 32]);
    }
    __syncthreads();
    short8 af[4], bfr[2];
    #pragma unroll
    for (int i = 0; i < 4; i++)
      af[i] = *(const short8*)&As[(wm + i * 16 + lcol) * 32 + quad * 8];
    #pragma unroll
    for (int j = 0; j < 2; j++)
      bfr[j] = *(const short8*)&Bs[(wn + j * 16 + lcol) * 32 + quad * 8];
    #pragma unroll
    for (int i = 0; i < 4; i++)
      #pragma unroll
      for (int j = 0; j < 2; j++)
        acc[i][j] = __builtin_amdgcn_mfma_f32_16x16x32_bf16(af[i], bfr[j], acc[i][j], 0, 0, 0);
  }

  #pragma unroll
  for (int i = 0; i < 4; i++) {
    #pragma unroll
    for (int j = 0; j < 2; j++) {
      int col = n0 + wn + j * 16 + lcol;
      float bv = bias[col];
      #pragma unroll
      for (int r = 0; r < 4; r++) {
        int row = m0 + wm + i * 16 + quad * 4 + r;
        float v = acc[i][j][r] + bv;
        if (Cf) Cf[(size_t)row * N + col] = v;
        else    Cb[(size_t)row * N + col] = f2bf(v);
      }
    }
  }
}

// ---------------- fused causal MLA attention (s-range split across blocks) ----------------
// Block: 4 waves = 4 heads, 32 q-rows (R5-proven body, no spill). Grid 1024:
//   slot = gid>>8: 0 = part0/heavy(qt=63-qi), 1 = part0/light(qt=qi),
//                  2 = part1/heavy,            3 = part1/light.
// part p computes s-tiles [p? nth:0, p? nt:nth), nth=(nt+1)>>1. No-max softmax
// => partials merge by pure addition in attn_merge. 48KB LDS -> 3 blocks/CU.
__global__ __launch_bounds__(256, 2) void attn_mla(
    const unsigned short* __restrict__ kq,   // [B*T][NKQ]
    const unsigned short* __restrict__ KlT,  // [B][L][T]
    unsigned short* __restrict__ O0,         // [B*T][NH*L] partial, part 0
    unsigned short* __restrict__ O1,         // partial, part 1
    float* __restrict__ lpart) {             // [2][B][NH][T]
  __shared__ __align__(16) unsigned short Kr[64 * 128];     // [s][l] swizzled 16KB
  __shared__ __align__(16) unsigned short Kt[128 * 64];     // [l][s] swizzled 16KB
  __shared__ __align__(16) unsigned short Pls[4][32 * 64];  // per-wave P     16KB

  const int tid  = threadIdx.x;
  const int wave = tid >> 6, lane = tid & 63;
  const int lcol = lane & 15, quad = lane >> 4;
  const int gid  = blockIdx.x;
  const int slot = gid >> 8, c = gid & 255;
  const int hg   = c >> 5, qi = c & 31;
  const int b    = hg >> 2;
  const int h    = (hg & 3) * 4 + wave;
  const int qt32 = (slot & 1) ? qi : (63 - qi);  // 32-row q-tile index
  const int part = slot >> 1;
  const size_t rowbase = (size_t)b * T_;
  const int q0 = qt32 * 32;
  unsigned short* Pw = &Pls[wave][0];

  const int nt  = (qt32 >> 1) + 1;     // total s-tiles of 64
  const int nth = (nt + 1) >> 1;
  const int ts0 = part ? nth : 0;
  const int ts1 = part ? nt : nth;

  // Q fragments (A-layout m=lane&15, k=quad*8+j); scale*log2e pre-folded
  short8 qf[2][4];
  #pragma unroll
  for (int i = 0; i < 2; i++) {
    const unsigned short* qp = kq + (rowbase + q0 + i * 16 + lcol) * NKQ + L_ + h * L_;
    #pragma unroll
    for (int kc = 0; kc < 4; kc++)
      qf[i][kc] = *(const short8*)(qp + kc * 32 + quad * 8);
  }

  f32x4 acco[2][8];
  #pragma unroll
  for (int i = 0; i < 2; i++)
    #pragma unroll
    for (int ns = 0; ns < 8; ns++) acco[i][ns] = (f32x4){0.f, 0.f, 0.f, 0.f};
  float lsum[2][4];
  #pragma unroll
  for (int i = 0; i < 2; i++)
    #pragma unroll
    for (int r = 0; r < 4; r++) lsum[i][r] = 0.f;

  for (int ts = ts0; ts < ts1; ts++) {
    const int s0 = ts * 64;
    __syncthreads();
    // stage Kr (64x128): swizzle uses the ACTUAL row&7 per sub-load
    #pragma unroll
    for (int kk = 0; kk < 4; kk++) {
      int r0 = wave * 16 + kk * 4;
      int rg = r0 + (lane >> 4);
      int cl = ((lane & 15) ^ (rg & 7)) * 8;
      GLD16(kq + (rowbase + s0 + rg) * NKQ + cl, &Kr[r0 * 128]);
    }
    // stage Kt (128x64) from KlT
    #pragma unroll
    for (int kk = 0; kk < 4; kk++) {
      int r0 = wave * 32 + kk * 8;
      int rg = r0 + (lane >> 3);
      int cl = ((lane & 7) ^ (rg & 7)) * 8;
      GLD16(KlT + ((size_t)b * L_ + rg) * T_ + s0 + cl, &Kt[r0 * 64]);
    }
    __syncthreads();

    // S(32x64) = Q @ K^T
    f32x4 accs[2][4];
    #pragma unroll
    for (int i = 0; i < 2; i++)
      #pragma unroll
      for (int ns = 0; ns < 4; ns++) accs[i][ns] = (f32x4){0.f, 0.f, 0.f, 0.f};
    #pragma unroll
    for (int kc = 0; kc < 4; kc++)
      #pragma unroll
      for (int ns = 0; ns < 4; ns++) {
        short8 bfrag = *(const short8*)&Kr[(ns * 16 + lcol) * 128 +
                                           (((kc * 4 + quad) ^ (lcol & 7)) * 8)];
        #pragma unroll
        for (int i = 0; i < 2; i++)
          accs[i][ns] = __builtin_amdgcn_mfma_f32_16x16x32_bf16(qf[i][kc], bfrag, accs[i][ns], 0, 0, 0);
      }

    // p = 2^s (log2e folded); truncate to bf16, lsum from truncated value
    const bool diag = (ts == nt - 1);
    #pragma unroll
    for (int i = 0; i < 2; i++)
      #pragma unroll
      for (int ns = 0; ns < 4; ns++)
        #pragma unroll
        for (int r = 0; r < 4; r++) {
          float v = accs[i][ns][r];
          int sg = ns * 16 + lcol;
          int qg = (qt32 & 1) * 32 + i * 16 + quad * 4 + r;
          if (diag && sg > qg) v = -1e30f;
          float e = __builtin_amdgcn_exp2f(v);
          unsigned eu = __float_as_uint(e) & 0xffff0000u;
          lsum[i][r] += __uint_as_float(eu);
          int row = i * 16 + quad * 4 + r;
          int col = ns * 16 + lcol;
          int phys = ((col >> 3) ^ (row & 7));
          Pw[row * 64 + phys * 8 + (col & 7)] = (unsigned short)(eu >> 16);
        }

    // O(32x128) += P(32x64) @ K(64x128)  (Pw wave-private: no barrier)
    #pragma unroll
    for (int kc2 = 0; kc2 < 2; kc2++) {
      short8 pa[2];
      #pragma unroll
      for (int i = 0; i < 2; i++)
        pa[i] = *(const short8*)&Pw[(i * 16 + lcol) * 64 +
                                    (((kc2 * 4 + quad) ^ (lcol & 7)) * 8)];
      #pragma unroll
      for (int ns = 0; ns < 8; ns++) {
        short8 bfrag = *(const short8*)&Kt[(ns * 16 + lcol) * 64 +
                                           (((kc2 * 4 + quad) ^ (lcol & 7)) * 8)];
        #pragma unroll
        for (int i = 0; i < 2; i++)
          acco[i][ns] = __builtin_amdgcn_mfma_f32_16x16x32_bf16(pa[i], bfrag, acco[i][ns], 0, 0, 0);
      }
    }
  }

  // reduce row sums across the 16 lcol lanes
  #pragma unroll
  for (int i = 0; i < 2; i++)
    #pragma unroll
    for (int r = 0; r < 4; r++) {
      float s = lsum[i][r];
      #pragma unroll
      for (int off = 1; off < 16; off <<= 1) s += __shfl_xor(s, off, 64);
      lsum[i][r] = s;
    }

  // write partial lsum (lanes with lcol==0 cover all 32 rows)
  float* lp = lpart + (size_t)part * (B_ * NH_ * T_) + ((size_t)b * NH_ + h) * T_ + q0;
  if (lcol == 0) {
    #pragma unroll
    for (int i = 0; i < 2; i++)
      #pragma unroll
      for (int r = 0; r < 4; r++)
        lp[i * 16 + quad * 4 + r] = lsum[i][r];
  }

  // write partial O (unnormalized, bf16)
  unsigned short* Op = part ? O1 : O0;
  #pragma unroll
  for (int i = 0; i < 2; i++)
    #pragma unroll
    for (int ns = 0; ns < 8; ns++)
      #pragma unroll
      for (int r = 0; r < 4; r++) {
        int qg = q0 + i * 16 + quad * 4 + r;
        Op[(rowbase + qg) * (NH_ * L_) + h * L_ + ns * 16 + lcol] = f2bf(acco[i][ns][r]);
      }
}

// ---------------- merge the two s-partitions: y = (O0+O1)/(l0+l1), in-place O0 ----------------
__global__ void attn_merge(unsigned short* __restrict__ O0,
                           const unsigned short* __restrict__ O1,
                           const float* __restrict__ lpart) {
  int idx = (blockIdx.x * 256 + threadIdx.x) * 8;
  int row = idx >> 11;               // / (NH_*L_)
  int col = idx & 2047;
  int h   = col >> 7;
  int t   = row & (T_ - 1);
  int bb  = row >> 11;
  const float* lp = lpart + ((size_t)bb * NH_ + h) * T_ + t;
  float inv = 1.f / (lp[0] + lp[(size_t)B_ * NH_ * T_]);
  short8 a = *(const short8*)(O0 + idx);
  short8 c = *(const short8*)(O1 + idx);
  short8 o;
  #pragma unroll
  for (int j = 0; j < 8; j++) {
    float fa = __uint_as_float(((unsigned)(unsigned short)a[j]) << 16);
    float fc = __uint_as_float(((unsigned)(unsigned short)c[j]) << 16);
    o[j] = (short)f2bf((fa + fc) * inv);
  }
  *(short8*)(O0 + idx) = o;
}

extern "C" void kernel_launch(void* const* d_in, const int* in_sizes, int n_in,
                              void* d_out, int out_size, void* d_ws, size_t ws_size,
                              hipStream_t stream) {
  const float* x      = (const float*)d_in[0];
  const float* W_lat  = (const float*)d_in[1];
  const float* b_lat  = (const float*)d_in[2];
  const float* W_d    = (const float*)d_in[3];
  const float* b_d    = (const float*)d_in[4];
  const float* W_proj = (const float*)d_in[5];
  const float* b_proj = (const float*)d_in[6];
  float* out = (float*)d_out;

  // workspace layout (bf16 buffers, 16B aligned)
  unsigned short* x_bf   = (unsigned short*)d_ws;                  // [4096][2048]
  unsigned short* BtCat  = x_bf   + (size_t)MTOK * C_;             // [2176][2048]
  unsigned short* WprojT = BtCat  + (size_t)NKQ * C_;              // [2048][2048]
  unsigned short* kqbuf  = WprojT + (size_t)C_ * (NH_ * L_);       // [4096][2176]
  unsigned short* O0     = kqbuf  + (size_t)MTOK * NKQ;            // [4096][2048]
  unsigned short* O1     = O0     + (size_t)MTOK * (NH_ * L_);     // [4096][2048]
  unsigned short* KlT    = O1     + (size_t)MTOK * (NH_ * L_);     // [2][128][2048]
  float*          lpart  = (float*)(KlT + (size_t)B_ * L_ * T_);   // [2][2][16][2048]
  float*          biascat = lpart + (size_t)2 * B_ * NH_ * T_;     // [2176]

  // 1. x -> bf16
  cvt_f32_bf16<<<(MTOK * C_) / 1024, 256, 0, stream>>>(x, x_bf, MTOK * C_);
  // 2. weights -> transposed bf16 (Bt layout); fold scale*log2e into W_d
  transpose_to_bf16<<<dim3(L_ / 32, C_ / 32), dim3(32, 8), 0, stream>>>(W_lat, BtCat, C_, L_, 1.f);
  transpose_to_bf16<<<dim3((NH_ * L_) / 32, C_ / 32), dim3(32, 8), 0, stream>>>(
      W_d, BtCat + (size_t)L_ * C_, C_, NH_ * L_, SCALE2_);
  transpose_to_bf16<<<dim3(C_ / 32, (NH_ * L_) / 32), dim3(32, 8), 0, stream>>>(
      W_proj, WprojT, NH_ * L_, C_, 1.f);
  make_bias_cat<<<(NKQ + 255) / 256, 256, 0, stream>>>(b_lat, b_d, biascat);
  // 3. kq = x @ [W_lat | scale*log2e*W_d] + bias (bf16 out)
  gemm_bt_bias64<<<dim3(MTOK / 128, NKQ / 64), 256, 0, stream>>>(
      x_bf, BtCat, biascat, kqbuf, nullptr, MTOK, NKQ, C_);
  // 4. latent transpose for PV staging
  transpose_lat<<<dim3(T_ / 32, L_ / 32, B_), dim3(32, 8), 0, stream>>>(kqbuf, KlT);
  // 5. causal MLA attention: 1024 blocks, 2-way s-split, partial outputs
  attn_mla<<<1024, 256, 0, stream>>>(kqbuf, KlT, O0, O1, lpart);
  // 6. merge partials (in-place into O0)
  attn_merge<<<(MTOK * NH_ * L_) / (256 * 8), 256, 0, stream>>>(O0, O1, lpart);
  // 7. out = y @ W_proj + b_proj (fp32 out)
  gemm_bt_bias64<<<dim3(MTOK / 128, C_ / 64), 256, 0, stream>>>(
      O0, WprojT, b_proj, nullptr, out, MTOK, C_, C_);
}